// Round 18
// baseline (26.558 us; speedup 1.0000x reference)
//
#include <hip/hip_runtime.h>
#include <hip/hip_bf16.h>

typedef __attribute__((ext_vector_type(8))) short bf16x8;
typedef __attribute__((ext_vector_type(4))) float f32x4;
typedef __attribute__((ext_vector_type(16))) float f32x16;
typedef __attribute__((ext_vector_type(2))) unsigned int u32x2;
typedef unsigned short u16;
typedef unsigned int u32;

#define EMB 128
#define LOG2E 1.44269504088896f

// round-to-nearest-even fp32 -> bf16
static __device__ __forceinline__ u16 f2bf(float f) {
    union { float f; u32 u; } v; v.f = f;
    u32 u = v.u;
    return (u16)((u + 0x7FFFu + ((u >> 16) & 1u)) >> 16);
}

static __device__ __forceinline__ u32 cvtpk(float a, float b) {
    u32 r;
    asm("v_cvt_pk_bf16_f32 %0, %1, %2" : "=v"(r) : "v"(a), "v"(b));
    return r;
}

static __device__ __forceinline__ float vexp2(float x) {
    float r;
    asm("v_exp_f32 %0, %1" : "=v"(r) : "v"(x));
    return r;
}

// exchange: a' = [a.lo32 | b.lo32(partner)], b' = [a.hi32(partner) | b.hi32]
static __device__ __forceinline__ void plswap(u32& a, u32& b) {
#if __has_builtin(__builtin_amdgcn_permlane32_swap)
    u32x2 r = __builtin_amdgcn_permlane32_swap(a, b, false, false);
    a = r[0]; b = r[1];
#else
    u32 sa = __shfl_xor(a, 32), sb = __shfl_xor(b, 32);
    bool hi = (threadIdx.x & 32) != 0;
    u32 na = hi ? sb : a;
    u32 nb = hi ? b : sa;
    a = na; b = nb;
#endif
}

// ---------------------------------------------------------------------------
// Single fully fused kernel (r17-green base). Deltas this round:
//  (a) Wo->LDS conversion moved into phase-3 head: barrier right after the
//      kf loads (Ks then dead), wob stores overlap the qt-loop compute.
//  (b) Phase 4 uses swapped MFMA operands -> thread holds 4 consecutive
//      out columns of one token -> float4 stores (8 vs 32 stores), one
//      mask load per thread.
//  (c) s_setprio(1) around phase-3 MFMA clusters (r11-green).
// LDS map (132 KB):
//   [0,      34816)  Xs   : LN'd X, [128 tok][136 u16]  (reused as ctxs)
//   [34816,  67584)  Qs   : [8 h][128 tok][16 d] u16, XOR-swz idx^((tok&4)<<1)
//   [67584, 100352)  Ks   : same as Qs (reused as swizzled Wo in phase 3)
//   [100352,135168)  Vs   : [8 h][16 d][136 tok-pitch] u16
__global__ void __launch_bounds__(512) k_fused(const float* __restrict__ pe,
        const float* __restrict__ g, const float* __restrict__ bia,
        const float* __restrict__ wq_f, const float* __restrict__ wk_f,
        const float* __restrict__ wv_f, const float* __restrict__ wo_f,
        const float* __restrict__ bq, const float* __restrict__ bk,
        const float* __restrict__ bv, const float* __restrict__ bo,
        const float* __restrict__ mask, float* __restrict__ out) {
    __shared__ __align__(16) char smem[135168];
    u16* Xs = reinterpret_cast<u16*>(smem);            // pitch 136
    u16* Qs = reinterpret_cast<u16*>(smem + 34816);
    u16* Ks = reinterpret_cast<u16*>(smem + 67584);
    u16* Vs = reinterpret_cast<u16*>(smem + 100352);
    char* ctxs = smem;                                  // 256B-pitch, swizzled
    char* wob = smem + 67584;                           // Wo bf16, 256B-pitch, swizzled

    int tid = threadIdx.x;
    int seq = blockIdx.x;
    int lane = tid & 63, h = tid >> 6;
    int lo = lane & 15, hi = lane >> 4;

    // ---- QKV W fragments: gather fp32 directly, pack with cvtpk (r16) ----
    bf16x8 bf[3][4];
    {
        const float* wsrc0 = wq_f + h * 16 + lo;
        const float* wsrc1 = wk_f + h * 16 + lo;
        const float* wsrc2 = wv_f + h * 16 + lo;
#pragma unroll
        for (int mat = 0; mat < 3; ++mat) {
            const float* ws = mat == 0 ? wsrc0 : mat == 1 ? wsrc1 : wsrc2;
#pragma unroll
            for (int kk = 0; kk < 4; ++kk) {
                const float* base = ws + (kk * 32 + hi * 8) * 128;
                union { u32 w[4]; bf16x8 v; } u;
                u.w[0] = cvtpk(base[0],   base[128]);
                u.w[1] = cvtpk(base[256], base[384]);
                u.w[2] = cvtpk(base[512], base[640]);
                u.w[3] = cvtpk(base[768], base[896]);
                bf[mat][kk] = u.v;
            }
        }
    }
    float4 bq4 = *reinterpret_cast<const float4*>(bq + h * 16 + hi * 4);
    float4 bk4 = *reinterpret_cast<const float4*>(bk + h * 16 + hi * 4);
    float bv_ = bv[h * 16 + lo];

    // ---- Wo prefetch (transposed ownership, r17): thread i owns (n, k0..k0+3).
    float wpre[8][4];
#pragma unroll
    for (int i = 0; i < 8; ++i) {
        int idx = i * 512 + tid;        // 0..4095
        int n = idx & 127;
        int k0 = (idx >> 7) * 4;
#pragma unroll
        for (int j = 0; j < 4; ++j)
            wpre[i][j] = wo_f[(k0 + j) * 128 + n];
    }

    // ---- Phase 1: LayerNorm, 4 threads/token, 128 tokens (r14 verbatim) ----
    {
        int tl = tid >> 2;
        int q = tid & 3;
        const float4* src = reinterpret_cast<const float4*>(pe + (size_t)(seq * 128 + tl) * EMB);
        float4 v[8];
        float s = 0.f, ss = 0.f;
#pragma unroll
        for (int i = 0; i < 8; ++i) {
            v[i] = src[i * 4 + q];
            s += v[i].x + v[i].y + v[i].z + v[i].w;
            ss += v[i].x * v[i].x + v[i].y * v[i].y + v[i].z * v[i].z + v[i].w * v[i].w;
        }
        s += __shfl_xor(s, 1); ss += __shfl_xor(ss, 1);
        s += __shfl_xor(s, 2); ss += __shfl_xor(ss, 2);
        float mean = s * (1.f / EMB);
        float var = ss * (1.f / EMB) - mean * mean;
        float rstd = rsqrtf(var + 1e-5f);
#pragma unroll
        for (int i = 0; i < 8; ++i) {
            int c = i * 16 + q * 4;
            float4 gg = *reinterpret_cast<const float4*>(g + c);
            float4 bb = *reinterpret_cast<const float4*>(bia + c);
            uint2 packed;
            packed.x = (u32)f2bf((v[i].x - mean) * rstd * gg.x + bb.x)
                     | ((u32)f2bf((v[i].y - mean) * rstd * gg.y + bb.y) << 16);
            packed.y = (u32)f2bf((v[i].z - mean) * rstd * gg.z + bb.z)
                     | ((u32)f2bf((v[i].w - mean) * rstd * gg.w + bb.w) << 16);
            *reinterpret_cast<uint2*>(&Xs[tl * 136 + c]) = packed;
        }
    }
    __syncthreads();

    // ---- Phase 2: per-head QKV GEMM (W in regs) -> LDS (r14 verbatim) ----
    {
#pragma unroll
        for (int sub = 0; sub < 8; ++sub) {
            bf16x8 a[4];
#pragma unroll
            for (int kk = 0; kk < 4; ++kk)
                a[kk] = *reinterpret_cast<const bf16x8*>(&Xs[(sub * 16 + lo) * 136 + kk * 32 + hi * 8]);
            f32x4 aq = {}, ak = {}, av = {};
#pragma unroll
            for (int kk = 0; kk < 4; ++kk) {
                // swapped: D col = token = lo, row = d = hi*4+j
                aq = __builtin_amdgcn_mfma_f32_16x16x32_bf16(bf[0][kk], a[kk], aq, 0, 0, 0);
                ak = __builtin_amdgcn_mfma_f32_16x16x32_bf16(bf[1][kk], a[kk], ak, 0, 0, 0);
                // normal: D col = d = lo, row = token = hi*4+j
                av = __builtin_amdgcn_mfma_f32_16x16x32_bf16(a[kk], bf[2][kk], av, 0, 0, 0);
            }
            // Q/K packed write: token = sub*16+lo, d = hi*4..hi*4+3
            {
                int tok = sub * 16 + lo;
                int idx = ((h << 11) + tok * 16 + hi * 4) ^ ((tok & 4) << 1);
                uint2 pq, pk;
                pq.x = (u32)f2bf((aq[0] + bq4.x) * 0.25f) | ((u32)f2bf((aq[1] + bq4.y) * 0.25f) << 16);
                pq.y = (u32)f2bf((aq[2] + bq4.z) * 0.25f) | ((u32)f2bf((aq[3] + bq4.w) * 0.25f) << 16);
                pk.x = (u32)f2bf(ak[0] + bk4.x) | ((u32)f2bf(ak[1] + bk4.y) << 16);
                pk.y = (u32)f2bf(ak[2] + bk4.z) | ((u32)f2bf(ak[3] + bk4.w) << 16);
                *reinterpret_cast<uint2*>(&Qs[idx]) = pq;
                *reinterpret_cast<uint2*>(&Ks[idx]) = pk;
            }
            // V packed write: [d=lo][tok], tok = sub*16 + hi*4 + j
            {
                int tokv = sub * 16 + hi * 4;
                uint2 pv;
                pv.x = (u32)f2bf(av[0] + bv_) | ((u32)f2bf(av[1] + bv_) << 16);
                pv.y = (u32)f2bf(av[2] + bv_) | ((u32)f2bf(av[3] + bv_) << 16);
                *reinterpret_cast<uint2*>(&Vs[h * 2176 + lo * 136 + tokv]) = pv;
            }
        }
    }
    __syncthreads();

    // ---- Phase 3: attention; Wo conversion folded into its head ----
    {
        int lo2 = lane & 31, hi2 = lane >> 5;
        int swz = (lo2 & 4) << 1;            // tok&4 == lo2&4 for tok = t*32+lo2
        const f32x16 zero = {};

        bf16x8 kf[4];
#pragma unroll
        for (int t = 0; t < 4; ++t)
            kf[t] = *reinterpret_cast<const bf16x8*>(
                &Ks[(h << 11) + (((t * 32 + lo2) * 16 + hi2 * 8) ^ swz)]);
        __syncthreads();   // all waves' Ks reads done -> Ks region dead

        // Wo regs -> bf16 into dead Ks region; stores drain under the
        // qt-loop's compute (disjoint from Qs/Vs/ctxs).
#pragma unroll
        for (int i = 0; i < 8; ++i) {
            int idx = i * 512 + tid;
            int n = idx & 127;
            int k0 = (idx >> 7) * 4;
            uint2 pw;
            pw.x = cvtpk(wpre[i][0], wpre[i][1]);
            pw.y = cvtpk(wpre[i][2], wpre[i][3]);
            *reinterpret_cast<uint2*>(wob + ((u32)(n * 256 + k0 * 2) ^ ((n & 7) << 4))) = pw;
        }

        for (int qt = 0; qt < 4; ++qt) {
            bf16x8 qf = *reinterpret_cast<const bf16x8*>(
                &Qs[(h << 11) + (((qt * 32 + lo2) * 16 + hi2 * 8) ^ swz)]);
            f32x16 s[4];
            __builtin_amdgcn_s_setprio(1);
#pragma unroll
            for (int t = 0; t < 4; ++t)
                s[t] = __builtin_amdgcn_mfma_f32_32x32x16_bf16(kf[t], qf, zero, 0, 0, 0);
            __builtin_amdgcn_s_setprio(0);

            // tree max (depth ~6)
            float mA[16];
#pragma unroll
            for (int i = 0; i < 16; ++i)
                mA[i] = fmaxf(fmaxf(s[0][i], s[1][i]), fmaxf(s[2][i], s[3][i]));
#pragma unroll
            for (int i = 0; i < 8; ++i) mA[i] = fmaxf(mA[i], mA[i + 8]);
#pragma unroll
            for (int i = 0; i < 4; ++i) mA[i] = fmaxf(mA[i], mA[i + 4]);
            float m = fmaxf(fmaxf(mA[0], mA[1]), fmaxf(mA[2], mA[3]));
            m = fmaxf(m, __shfl_xor(m, 32));
            float m2 = m * LOG2E;

            float sm0 = 0.f, sm1 = 0.f, sm2 = 0.f, sm3 = 0.f;
#pragma unroll
            for (int t = 0; t < 4; ++t)
#pragma unroll
                for (int r = 0; r < 16; ++r) {
                    float p = vexp2(__builtin_fmaf(s[t][r], LOG2E, -m2));
                    s[t][r] = p;
                    if (t == 0) sm0 += p; else if (t == 1) sm1 += p;
                    else if (t == 2) sm2 += p; else sm3 += p;
                }
            float sum = (sm0 + sm1) + (sm2 + sm3);
            sum += __shfl_xor(sum, 32);
            float inv = 1.f / sum;

            f32x16 o0 = {}, o1 = {};
#pragma unroll
            for (int c = 0; c < 8; ++c) {
                int t = c >> 1, hf = (c & 1) * 8;
                u32 x0 = cvtpk(s[t][hf + 0], s[t][hf + 1]);
                u32 x1 = cvtpk(s[t][hf + 2], s[t][hf + 3]);
                u32 y0 = cvtpk(s[t][hf + 4], s[t][hf + 5]);
                u32 y1 = cvtpk(s[t][hf + 6], s[t][hf + 7]);
                plswap(x0, y0);
                plswap(x1, y1);
                union { u32 wd[4]; bf16x8 v; } pb;
                pb.wd[0] = x0; pb.wd[1] = x1; pb.wd[2] = y0; pb.wd[3] = y1;
                bf16x8 va = *reinterpret_cast<const bf16x8*>(
                    &Vs[h * 2176 + (lo2 & 15) * 136 + c * 16 + hi2 * 8]);
                __builtin_amdgcn_s_setprio(1);
                if (c & 1)
                    o1 = __builtin_amdgcn_mfma_f32_32x32x16_bf16(va, pb.v, o1, 0, 0, 0);
                else
                    o0 = __builtin_amdgcn_mfma_f32_32x32x16_bf16(va, pb.v, o0, 0, 0, 0);
                __builtin_amdgcn_s_setprio(0);
            }

            int tok = qt * 32 + lo2;
            u32 off0 = (u32)(tok * 256 + h * 32 + 8 * hi2) ^ ((tok & 7) << 4);
            u32 off1 = (u32)(tok * 256 + h * 32 + 16 + 8 * hi2) ^ ((tok & 7) << 4);
            uint2 p0, p1;
            p0.x = cvtpk((o0[0] + o1[0]) * inv, (o0[1] + o1[1]) * inv);
            p0.y = cvtpk((o0[2] + o1[2]) * inv, (o0[3] + o1[3]) * inv);
            p1.x = cvtpk((o0[4] + o1[4]) * inv, (o0[5] + o1[5]) * inv);
            p1.y = cvtpk((o0[6] + o1[6]) * inv, (o0[7] + o1[7]) * inv);
            *reinterpret_cast<uint2*>(ctxs + off0) = p0;
            *reinterpret_cast<uint2*>(ctxs + off1) = p1;
        }
    }
    __syncthreads();   // ctx + wob both ready for all waves

    // ---- Phase 4: out-proj, swapped operands. Thread (lo,hi) holds
    // out[t = seq*128+h*16+lo][c*16 + hi*4 + j] -> float4 stores.
    {
        f32x4 acc[8];
#pragma unroll
        for (int c = 0; c < 8; ++c) acc[c] = f32x4{0.f, 0.f, 0.f, 0.f};
#pragma unroll
        for (int kk = 0; kk < 4; ++kk) {
            int tokrow = h * 16 + lo;
            u32 aoff = (u32)(tokrow * 256 + kk * 64 + hi * 16) ^ ((tokrow & 7) << 4);
            bf16x8 a = *reinterpret_cast<const bf16x8*>(ctxs + aoff);
#pragma unroll
            for (int c = 0; c < 8; ++c) {
                u32 boff = (u32)((c * 16 + lo) * 256 + kk * 64 + hi * 16) ^ ((lo & 7) << 4);
                bf16x8 b = *reinterpret_cast<const bf16x8*>(wob + boff);
                // swapped: D row = wo col (hi*4+j), D col = token (lo)
                acc[c] = __builtin_amdgcn_mfma_f32_16x16x32_bf16(b, a, acc[c], 0, 0, 0);
            }
        }
        int t = seq * 128 + h * 16 + lo;
        float mk = mask[t];
#pragma unroll
        for (int c = 0; c < 8; ++c) {
            float4 bo4 = *reinterpret_cast<const float4*>(bo + c * 16 + hi * 4);
            float4 o4;
            o4.x = (acc[c][0] + bo4.x) * mk;
            o4.y = (acc[c][1] + bo4.y) * mk;
            o4.z = (acc[c][2] + bo4.z) * mk;
            o4.w = (acc[c][3] + bo4.w) * mk;
            *reinterpret_cast<float4*>(out + (size_t)t * EMB + c * 16 + hi * 4) = o4;
        }
    }
}

// ---------------------------------------------------------------------------
extern "C" void kernel_launch(void* const* d_in, const int* in_sizes, int n_in,
                              void* d_out, int out_size, void* d_ws, size_t ws_size,
                              hipStream_t stream) {
    const float* pe   = (const float*)d_in[0];
    const float* mask = (const float*)d_in[1];
    const float* ln_g = (const float*)d_in[2];
    const float* ln_b = (const float*)d_in[3];
    const float* wq   = (const float*)d_in[4];
    const float* bq   = (const float*)d_in[5];
    const float* wk   = (const float*)d_in[6];
    const float* bk   = (const float*)d_in[7];
    const float* wv   = (const float*)d_in[8];
    const float* bv   = (const float*)d_in[9];
    const float* wo   = (const float*)d_in[10];
    const float* bo   = (const float*)d_in[11];
    float* out = (float*)d_out;

    hipLaunchKernelGGL(k_fused, dim3(256), dim3(512), 0, stream, pe, ln_g, ln_b,
                       wq, wk, wv, wo, bq, bk, bv, bo, mask, out);
}

// Round 19
// 25.403 us; speedup vs baseline: 1.0454x; 1.0454x over previous
//
#include <hip/hip_runtime.h>
#include <hip/hip_bf16.h>

typedef __attribute__((ext_vector_type(8))) short bf16x8;
typedef __attribute__((ext_vector_type(4))) float f32x4;
typedef __attribute__((ext_vector_type(16))) float f32x16;
typedef __attribute__((ext_vector_type(2))) unsigned int u32x2;
typedef unsigned short u16;
typedef unsigned int u32;

#define EMB 128
#define LOG2E 1.44269504088896f

// round-to-nearest-even fp32 -> bf16
static __device__ __forceinline__ u16 f2bf(float f) {
    union { float f; u32 u; } v; v.f = f;
    u32 u = v.u;
    return (u16)((u + 0x7FFFu + ((u >> 16) & 1u)) >> 16);
}

static __device__ __forceinline__ u32 cvtpk(float a, float b) {
    u32 r;
    asm("v_cvt_pk_bf16_f32 %0, %1, %2" : "=v"(r) : "v"(a), "v"(b));
    return r;
}

static __device__ __forceinline__ float vexp2(float x) {
    float r;
    asm("v_exp_f32 %0, %1" : "=v"(r) : "v"(x));
    return r;
}

// exchange: a' = [a.lo32 | b.lo32(partner)], b' = [a.hi32(partner) | b.hi32]
static __device__ __forceinline__ void plswap(u32& a, u32& b) {
#if __has_builtin(__builtin_amdgcn_permlane32_swap)
    u32x2 r = __builtin_amdgcn_permlane32_swap(a, b, false, false);
    a = r[0]; b = r[1];
#else
    u32 sa = __shfl_xor(a, 32), sb = __shfl_xor(b, 32);
    bool hi = (threadIdx.x & 32) != 0;
    u32 na = hi ? sb : a;
    u32 nb = hi ? b : sa;
    a = na; b = nb;
#endif
}

// ---------------------------------------------------------------------------
// Single fully fused kernel (r17-green base). Sole structural delta vs r17:
// the Wo->LDS conversion is folded into the phase-3 head (barrier right
// after the kf loads, then wob stores drain under the qt-loop compute) —
// removes the dedicated barrier-bounded phase 3.5. Phase 4 is r17-verbatim
// except the 32 redundant mask[t] loads are CSE'd to 4 (identical values).
// NO setprio, NO phase-4 operand swap (both regressed in r18).
// LDS map (132 KB):
//   [0,      34816)  Xs   : LN'd X, [128 tok][136 u16]  (reused as ctxs)
//   [34816,  67584)  Qs   : [8 h][128 tok][16 d] u16, XOR-swz idx^((tok&4)<<1)
//   [67584, 100352)  Ks   : same as Qs (reused as swizzled Wo in phase 3)
//   [100352,135168)  Vs   : [8 h][16 d][136 tok-pitch] u16
__global__ void __launch_bounds__(512) k_fused(const float* __restrict__ pe,
        const float* __restrict__ g, const float* __restrict__ bia,
        const float* __restrict__ wq_f, const float* __restrict__ wk_f,
        const float* __restrict__ wv_f, const float* __restrict__ wo_f,
        const float* __restrict__ bq, const float* __restrict__ bk,
        const float* __restrict__ bv, const float* __restrict__ bo,
        const float* __restrict__ mask, float* __restrict__ out) {
    __shared__ __align__(16) char smem[135168];
    u16* Xs = reinterpret_cast<u16*>(smem);            // pitch 136
    u16* Qs = reinterpret_cast<u16*>(smem + 34816);
    u16* Ks = reinterpret_cast<u16*>(smem + 67584);
    u16* Vs = reinterpret_cast<u16*>(smem + 100352);
    char* ctxs = smem;                                  // 256B-pitch, swizzled
    char* wob = smem + 67584;                           // Wo bf16, 256B-pitch, swizzled

    int tid = threadIdx.x;
    int seq = blockIdx.x;
    int lane = tid & 63, h = tid >> 6;
    int lo = lane & 15, hi = lane >> 4;

    // ---- QKV W fragments: gather fp32 directly, pack with cvtpk (r16) ----
    bf16x8 bf[3][4];
    {
        const float* wsrc0 = wq_f + h * 16 + lo;
        const float* wsrc1 = wk_f + h * 16 + lo;
        const float* wsrc2 = wv_f + h * 16 + lo;
#pragma unroll
        for (int mat = 0; mat < 3; ++mat) {
            const float* ws = mat == 0 ? wsrc0 : mat == 1 ? wsrc1 : wsrc2;
#pragma unroll
            for (int kk = 0; kk < 4; ++kk) {
                const float* base = ws + (kk * 32 + hi * 8) * 128;
                union { u32 w[4]; bf16x8 v; } u;
                u.w[0] = cvtpk(base[0],   base[128]);
                u.w[1] = cvtpk(base[256], base[384]);
                u.w[2] = cvtpk(base[512], base[640]);
                u.w[3] = cvtpk(base[768], base[896]);
                bf[mat][kk] = u.v;
            }
        }
    }
    float4 bq4 = *reinterpret_cast<const float4*>(bq + h * 16 + hi * 4);
    float4 bk4 = *reinterpret_cast<const float4*>(bk + h * 16 + hi * 4);
    float bv_ = bv[h * 16 + lo];

    // ---- Wo prefetch (transposed ownership, r17): thread i owns (n, k0..k0+3).
    float wpre[8][4];
#pragma unroll
    for (int i = 0; i < 8; ++i) {
        int idx = i * 512 + tid;        // 0..4095
        int n = idx & 127;
        int k0 = (idx >> 7) * 4;
#pragma unroll
        for (int j = 0; j < 4; ++j)
            wpre[i][j] = wo_f[(k0 + j) * 128 + n];
    }

    // ---- Phase 1: LayerNorm, 4 threads/token, 128 tokens (r14 verbatim) ----
    {
        int tl = tid >> 2;
        int q = tid & 3;
        const float4* src = reinterpret_cast<const float4*>(pe + (size_t)(seq * 128 + tl) * EMB);
        float4 v[8];
        float s = 0.f, ss = 0.f;
#pragma unroll
        for (int i = 0; i < 8; ++i) {
            v[i] = src[i * 4 + q];
            s += v[i].x + v[i].y + v[i].z + v[i].w;
            ss += v[i].x * v[i].x + v[i].y * v[i].y + v[i].z * v[i].z + v[i].w * v[i].w;
        }
        s += __shfl_xor(s, 1); ss += __shfl_xor(ss, 1);
        s += __shfl_xor(s, 2); ss += __shfl_xor(ss, 2);
        float mean = s * (1.f / EMB);
        float var = ss * (1.f / EMB) - mean * mean;
        float rstd = rsqrtf(var + 1e-5f);
#pragma unroll
        for (int i = 0; i < 8; ++i) {
            int c = i * 16 + q * 4;
            float4 gg = *reinterpret_cast<const float4*>(g + c);
            float4 bb = *reinterpret_cast<const float4*>(bia + c);
            uint2 packed;
            packed.x = (u32)f2bf((v[i].x - mean) * rstd * gg.x + bb.x)
                     | ((u32)f2bf((v[i].y - mean) * rstd * gg.y + bb.y) << 16);
            packed.y = (u32)f2bf((v[i].z - mean) * rstd * gg.z + bb.z)
                     | ((u32)f2bf((v[i].w - mean) * rstd * gg.w + bb.w) << 16);
            *reinterpret_cast<uint2*>(&Xs[tl * 136 + c]) = packed;
        }
    }
    __syncthreads();

    // ---- Phase 2: per-head QKV GEMM (W in regs) -> LDS (r14 verbatim) ----
    {
#pragma unroll
        for (int sub = 0; sub < 8; ++sub) {
            bf16x8 a[4];
#pragma unroll
            for (int kk = 0; kk < 4; ++kk)
                a[kk] = *reinterpret_cast<const bf16x8*>(&Xs[(sub * 16 + lo) * 136 + kk * 32 + hi * 8]);
            f32x4 aq = {}, ak = {}, av = {};
#pragma unroll
            for (int kk = 0; kk < 4; ++kk) {
                // swapped: D col = token = lo, row = d = hi*4+j
                aq = __builtin_amdgcn_mfma_f32_16x16x32_bf16(bf[0][kk], a[kk], aq, 0, 0, 0);
                ak = __builtin_amdgcn_mfma_f32_16x16x32_bf16(bf[1][kk], a[kk], ak, 0, 0, 0);
                // normal: D col = d = lo, row = token = hi*4+j
                av = __builtin_amdgcn_mfma_f32_16x16x32_bf16(a[kk], bf[2][kk], av, 0, 0, 0);
            }
            // Q/K packed write: token = sub*16+lo, d = hi*4..hi*4+3
            {
                int tok = sub * 16 + lo;
                int idx = ((h << 11) + tok * 16 + hi * 4) ^ ((tok & 4) << 1);
                uint2 pq, pk;
                pq.x = (u32)f2bf((aq[0] + bq4.x) * 0.25f) | ((u32)f2bf((aq[1] + bq4.y) * 0.25f) << 16);
                pq.y = (u32)f2bf((aq[2] + bq4.z) * 0.25f) | ((u32)f2bf((aq[3] + bq4.w) * 0.25f) << 16);
                pk.x = (u32)f2bf(ak[0] + bk4.x) | ((u32)f2bf(ak[1] + bk4.y) << 16);
                pk.y = (u32)f2bf(ak[2] + bk4.z) | ((u32)f2bf(ak[3] + bk4.w) << 16);
                *reinterpret_cast<uint2*>(&Qs[idx]) = pq;
                *reinterpret_cast<uint2*>(&Ks[idx]) = pk;
            }
            // V packed write: [d=lo][tok], tok = sub*16 + hi*4 + j
            {
                int tokv = sub * 16 + hi * 4;
                uint2 pv;
                pv.x = (u32)f2bf(av[0] + bv_) | ((u32)f2bf(av[1] + bv_) << 16);
                pv.y = (u32)f2bf(av[2] + bv_) | ((u32)f2bf(av[3] + bv_) << 16);
                *reinterpret_cast<uint2*>(&Vs[h * 2176 + lo * 136 + tokv]) = pv;
            }
        }
    }
    __syncthreads();

    // ---- Phase 3: attention; Wo conversion folded into its head ----
    {
        int lo2 = lane & 31, hi2 = lane >> 5;
        int swz = (lo2 & 4) << 1;            // tok&4 == lo2&4 for tok = t*32+lo2
        const f32x16 zero = {};

        bf16x8 kf[4];
#pragma unroll
        for (int t = 0; t < 4; ++t)
            kf[t] = *reinterpret_cast<const bf16x8*>(
                &Ks[(h << 11) + (((t * 32 + lo2) * 16 + hi2 * 8) ^ swz)]);
        __syncthreads();   // all waves' Ks reads done -> Ks region dead

        // Wo regs -> bf16 into dead Ks region; stores drain under the
        // qt-loop's compute (region disjoint from Qs/Vs/ctxs).
#pragma unroll
        for (int i = 0; i < 8; ++i) {
            int idx = i * 512 + tid;
            int n = idx & 127;
            int k0 = (idx >> 7) * 4;
            uint2 pw;
            pw.x = cvtpk(wpre[i][0], wpre[i][1]);
            pw.y = cvtpk(wpre[i][2], wpre[i][3]);
            *reinterpret_cast<uint2*>(wob + ((u32)(n * 256 + k0 * 2) ^ ((n & 7) << 4))) = pw;
        }

        for (int qt = 0; qt < 4; ++qt) {
            bf16x8 qf = *reinterpret_cast<const bf16x8*>(
                &Qs[(h << 11) + (((qt * 32 + lo2) * 16 + hi2 * 8) ^ swz)]);
            f32x16 s[4];
#pragma unroll
            for (int t = 0; t < 4; ++t)
                s[t] = __builtin_amdgcn_mfma_f32_32x32x16_bf16(kf[t], qf, zero, 0, 0, 0);

            // tree max (depth ~6)
            float mA[16];
#pragma unroll
            for (int i = 0; i < 16; ++i)
                mA[i] = fmaxf(fmaxf(s[0][i], s[1][i]), fmaxf(s[2][i], s[3][i]));
#pragma unroll
            for (int i = 0; i < 8; ++i) mA[i] = fmaxf(mA[i], mA[i + 8]);
#pragma unroll
            for (int i = 0; i < 4; ++i) mA[i] = fmaxf(mA[i], mA[i + 4]);
            float m = fmaxf(fmaxf(mA[0], mA[1]), fmaxf(mA[2], mA[3]));
            m = fmaxf(m, __shfl_xor(m, 32));
            float m2 = m * LOG2E;

            float sm0 = 0.f, sm1 = 0.f, sm2 = 0.f, sm3 = 0.f;
#pragma unroll
            for (int t = 0; t < 4; ++t)
#pragma unroll
                for (int r = 0; r < 16; ++r) {
                    float p = vexp2(__builtin_fmaf(s[t][r], LOG2E, -m2));
                    s[t][r] = p;
                    if (t == 0) sm0 += p; else if (t == 1) sm1 += p;
                    else if (t == 2) sm2 += p; else sm3 += p;
                }
            float sum = (sm0 + sm1) + (sm2 + sm3);
            sum += __shfl_xor(sum, 32);
            float inv = 1.f / sum;

            f32x16 o0 = {}, o1 = {};
#pragma unroll
            for (int c = 0; c < 8; ++c) {
                int t = c >> 1, hf = (c & 1) * 8;
                u32 x0 = cvtpk(s[t][hf + 0], s[t][hf + 1]);
                u32 x1 = cvtpk(s[t][hf + 2], s[t][hf + 3]);
                u32 y0 = cvtpk(s[t][hf + 4], s[t][hf + 5]);
                u32 y1 = cvtpk(s[t][hf + 6], s[t][hf + 7]);
                plswap(x0, y0);
                plswap(x1, y1);
                union { u32 wd[4]; bf16x8 v; } pb;
                pb.wd[0] = x0; pb.wd[1] = x1; pb.wd[2] = y0; pb.wd[3] = y1;
                bf16x8 va = *reinterpret_cast<const bf16x8*>(
                    &Vs[h * 2176 + (lo2 & 15) * 136 + c * 16 + hi2 * 8]);
                if (c & 1)
                    o1 = __builtin_amdgcn_mfma_f32_32x32x16_bf16(va, pb.v, o1, 0, 0, 0);
                else
                    o0 = __builtin_amdgcn_mfma_f32_32x32x16_bf16(va, pb.v, o0, 0, 0, 0);
            }

            int tok = qt * 32 + lo2;
            u32 off0 = (u32)(tok * 256 + h * 32 + 8 * hi2) ^ ((tok & 7) << 4);
            u32 off1 = (u32)(tok * 256 + h * 32 + 16 + 8 * hi2) ^ ((tok & 7) << 4);
            uint2 p0, p1;
            p0.x = cvtpk((o0[0] + o1[0]) * inv, (o0[1] + o1[1]) * inv);
            p0.y = cvtpk((o0[2] + o1[2]) * inv, (o0[3] + o1[3]) * inv);
            p1.x = cvtpk((o0[4] + o1[4]) * inv, (o0[5] + o1[5]) * inv);
            p1.y = cvtpk((o0[6] + o1[6]) * inv, (o0[7] + o1[7]) * inv);
            *reinterpret_cast<uint2*>(ctxs + off0) = p0;
            *reinterpret_cast<uint2*>(ctxs + off1) = p1;
        }
    }
    __syncthreads();   // ctx + wob both ready for all waves

    // ---- Phase 4: out-proj (r17 verbatim except mask CSE). Wave h does
    // tokens [h*16, h*16+16); col-contiguous scalar stores (coalesced). ----
    {
        f32x4 acc[8];
#pragma unroll
        for (int c = 0; c < 8; ++c) acc[c] = f32x4{0.f, 0.f, 0.f, 0.f};
#pragma unroll
        for (int kk = 0; kk < 4; ++kk) {
            int tokrow = h * 16 + lo;
            u32 aoff = (u32)(tokrow * 256 + kk * 64 + hi * 16) ^ ((tokrow & 7) << 4);
            bf16x8 a = *reinterpret_cast<const bf16x8*>(ctxs + aoff);
#pragma unroll
            for (int c = 0; c < 8; ++c) {
                u32 boff = (u32)((c * 16 + lo) * 256 + kk * 64 + hi * 16) ^ ((lo & 7) << 4);
                bf16x8 b = *reinterpret_cast<const bf16x8*>(wob + boff);
                acc[c] = __builtin_amdgcn_mfma_f32_16x16x32_bf16(a, b, acc[c], 0, 0, 0);
            }
        }
        // mask CSE: this thread's 4 token rows are t0+0..3
        int t0 = seq * 128 + h * 16 + hi * 4;
        float4 mk4 = *reinterpret_cast<const float4*>(mask + t0);
        float mk[4] = {mk4.x, mk4.y, mk4.z, mk4.w};
#pragma unroll
        for (int c = 0; c < 8; ++c) {
            int col = c * 16 + lo;
            float bval = bo[col];
#pragma unroll
            for (int j = 0; j < 4; ++j) {
                int t = t0 + j;
                out[(size_t)t * EMB + col] = (acc[c][j] + bval) * mk[j];
            }
        }
    }
}

// ---------------------------------------------------------------------------
extern "C" void kernel_launch(void* const* d_in, const int* in_sizes, int n_in,
                              void* d_out, int out_size, void* d_ws, size_t ws_size,
                              hipStream_t stream) {
    const float* pe   = (const float*)d_in[0];
    const float* mask = (const float*)d_in[1];
    const float* ln_g = (const float*)d_in[2];
    const float* ln_b = (const float*)d_in[3];
    const float* wq   = (const float*)d_in[4];
    const float* bq   = (const float*)d_in[5];
    const float* wk   = (const float*)d_in[6];
    const float* bk   = (const float*)d_in[7];
    const float* wv   = (const float*)d_in[8];
    const float* bv   = (const float*)d_in[9];
    const float* wo   = (const float*)d_in[10];
    const float* bo   = (const float*)d_in[11];
    float* out = (float*)d_out;

    hipLaunchKernelGGL(k_fused, dim3(256), dim3(512), 0, stream, pe, ln_g, ln_b,
                       wq, wk, wv, wo, bq, bk, bv, bo, mask, out);
}

// Round 20
// 24.276 us; speedup vs baseline: 1.0940x; 1.0464x over previous
//
#include <hip/hip_runtime.h>
#include <hip/hip_bf16.h>

typedef __attribute__((ext_vector_type(8))) short bf16x8;
typedef __attribute__((ext_vector_type(4))) float f32x4;
typedef __attribute__((ext_vector_type(16))) float f32x16;
typedef __attribute__((ext_vector_type(2))) unsigned int u32x2;
typedef unsigned short u16;
typedef unsigned int u32;

#define EMB 128
#define LOG2E 1.44269504088896f

static __device__ __forceinline__ u32 cvtpk(float a, float b) {
    u32 r;
    asm("v_cvt_pk_bf16_f32 %0, %1, %2" : "=v"(r) : "v"(a), "v"(b));
    return r;
}

static __device__ __forceinline__ float vexp2(float x) {
    float r;
    asm("v_exp_f32 %0, %1" : "=v"(r) : "v"(x));
    return r;
}

// exchange: a' = [a.lo32 | b.lo32(partner)], b' = [a.hi32(partner) | b.hi32]
static __device__ __forceinline__ void plswap(u32& a, u32& b) {
#if __has_builtin(__builtin_amdgcn_permlane32_swap)
    u32x2 r = __builtin_amdgcn_permlane32_swap(a, b, false, false);
    a = r[0]; b = r[1];
#else
    u32 sa = __shfl_xor(a, 32), sb = __shfl_xor(b, 32);
    bool hi = (threadIdx.x & 32) != 0;
    u32 na = hi ? sb : a;
    u32 nb = hi ? b : sa;
    a = na; b = nb;
#endif
}

// ---------------------------------------------------------------------------
// Single fully fused kernel (r19-green base). Sole delta this round: the
// f2bf-pair + shift/or packing in phases 1 and 2 replaced with single
// v_cvt_pk_bf16_f32 instructions (RTNE-identical values; hardware-verified
// when r10/r16 made the same swap with unchanged absmax).
// LDS map (132 KB):
//   [0,      34816)  Xs   : LN'd X, [128 tok][136 u16]  (reused as ctxs)
//   [34816,  67584)  Qs   : [8 h][128 tok][16 d] u16, XOR-swz idx^((tok&4)<<1)
//   [67584, 100352)  Ks   : same as Qs (reused as swizzled Wo in phase 3)
//   [100352,135168)  Vs   : [8 h][16 d][136 tok-pitch] u16
__global__ void __launch_bounds__(512) k_fused(const float* __restrict__ pe,
        const float* __restrict__ g, const float* __restrict__ bia,
        const float* __restrict__ wq_f, const float* __restrict__ wk_f,
        const float* __restrict__ wv_f, const float* __restrict__ wo_f,
        const float* __restrict__ bq, const float* __restrict__ bk,
        const float* __restrict__ bv, const float* __restrict__ bo,
        const float* __restrict__ mask, float* __restrict__ out) {
    __shared__ __align__(16) char smem[135168];
    u16* Xs = reinterpret_cast<u16*>(smem);            // pitch 136
    u16* Qs = reinterpret_cast<u16*>(smem + 34816);
    u16* Ks = reinterpret_cast<u16*>(smem + 67584);
    u16* Vs = reinterpret_cast<u16*>(smem + 100352);
    char* ctxs = smem;                                  // 256B-pitch, swizzled
    char* wob = smem + 67584;                           // Wo bf16, 256B-pitch, swizzled

    int tid = threadIdx.x;
    int seq = blockIdx.x;
    int lane = tid & 63, h = tid >> 6;
    int lo = lane & 15, hi = lane >> 4;

    // ---- QKV W fragments: gather fp32 directly, pack with cvtpk (r16) ----
    bf16x8 bf[3][4];
    {
        const float* wsrc0 = wq_f + h * 16 + lo;
        const float* wsrc1 = wk_f + h * 16 + lo;
        const float* wsrc2 = wv_f + h * 16 + lo;
#pragma unroll
        for (int mat = 0; mat < 3; ++mat) {
            const float* ws = mat == 0 ? wsrc0 : mat == 1 ? wsrc1 : wsrc2;
#pragma unroll
            for (int kk = 0; kk < 4; ++kk) {
                const float* base = ws + (kk * 32 + hi * 8) * 128;
                union { u32 w[4]; bf16x8 v; } u;
                u.w[0] = cvtpk(base[0],   base[128]);
                u.w[1] = cvtpk(base[256], base[384]);
                u.w[2] = cvtpk(base[512], base[640]);
                u.w[3] = cvtpk(base[768], base[896]);
                bf[mat][kk] = u.v;
            }
        }
    }
    float4 bq4 = *reinterpret_cast<const float4*>(bq + h * 16 + hi * 4);
    float4 bk4 = *reinterpret_cast<const float4*>(bk + h * 16 + hi * 4);
    float bv_ = bv[h * 16 + lo];

    // ---- Wo prefetch (transposed ownership, r17): thread i owns (n, k0..k0+3).
    float wpre[8][4];
#pragma unroll
    for (int i = 0; i < 8; ++i) {
        int idx = i * 512 + tid;        // 0..4095
        int n = idx & 127;
        int k0 = (idx >> 7) * 4;
#pragma unroll
        for (int j = 0; j < 4; ++j)
            wpre[i][j] = wo_f[(k0 + j) * 128 + n];
    }

    // ---- Phase 1: LayerNorm, 4 threads/token, 128 tokens ----
    {
        int tl = tid >> 2;
        int q = tid & 3;
        const float4* src = reinterpret_cast<const float4*>(pe + (size_t)(seq * 128 + tl) * EMB);
        float4 v[8];
        float s = 0.f, ss = 0.f;
#pragma unroll
        for (int i = 0; i < 8; ++i) {
            v[i] = src[i * 4 + q];
            s += v[i].x + v[i].y + v[i].z + v[i].w;
            ss += v[i].x * v[i].x + v[i].y * v[i].y + v[i].z * v[i].z + v[i].w * v[i].w;
        }
        s += __shfl_xor(s, 1); ss += __shfl_xor(ss, 1);
        s += __shfl_xor(s, 2); ss += __shfl_xor(ss, 2);
        float mean = s * (1.f / EMB);
        float var = ss * (1.f / EMB) - mean * mean;
        float rstd = rsqrtf(var + 1e-5f);
#pragma unroll
        for (int i = 0; i < 8; ++i) {
            int c = i * 16 + q * 4;
            float4 gg = *reinterpret_cast<const float4*>(g + c);
            float4 bb = *reinterpret_cast<const float4*>(bia + c);
            uint2 packed;
            packed.x = cvtpk((v[i].x - mean) * rstd * gg.x + bb.x,
                             (v[i].y - mean) * rstd * gg.y + bb.y);
            packed.y = cvtpk((v[i].z - mean) * rstd * gg.z + bb.z,
                             (v[i].w - mean) * rstd * gg.w + bb.w);
            *reinterpret_cast<uint2*>(&Xs[tl * 136 + c]) = packed;
        }
    }
    __syncthreads();

    // ---- Phase 2: per-head QKV GEMM (W in regs) -> LDS ----
    {
#pragma unroll
        for (int sub = 0; sub < 8; ++sub) {
            bf16x8 a[4];
#pragma unroll
            for (int kk = 0; kk < 4; ++kk)
                a[kk] = *reinterpret_cast<const bf16x8*>(&Xs[(sub * 16 + lo) * 136 + kk * 32 + hi * 8]);
            f32x4 aq = {}, ak = {}, av = {};
#pragma unroll
            for (int kk = 0; kk < 4; ++kk) {
                // swapped: D col = token = lo, row = d = hi*4+j
                aq = __builtin_amdgcn_mfma_f32_16x16x32_bf16(bf[0][kk], a[kk], aq, 0, 0, 0);
                ak = __builtin_amdgcn_mfma_f32_16x16x32_bf16(bf[1][kk], a[kk], ak, 0, 0, 0);
                // normal: D col = d = lo, row = token = hi*4+j
                av = __builtin_amdgcn_mfma_f32_16x16x32_bf16(a[kk], bf[2][kk], av, 0, 0, 0);
            }
            // Q/K packed write: token = sub*16+lo, d = hi*4..hi*4+3
            {
                int tok = sub * 16 + lo;
                int idx = ((h << 11) + tok * 16 + hi * 4) ^ ((tok & 4) << 1);
                uint2 pq, pk;
                pq.x = cvtpk((aq[0] + bq4.x) * 0.25f, (aq[1] + bq4.y) * 0.25f);
                pq.y = cvtpk((aq[2] + bq4.z) * 0.25f, (aq[3] + bq4.w) * 0.25f);
                pk.x = cvtpk(ak[0] + bk4.x, ak[1] + bk4.y);
                pk.y = cvtpk(ak[2] + bk4.z, ak[3] + bk4.w);
                *reinterpret_cast<uint2*>(&Qs[idx]) = pq;
                *reinterpret_cast<uint2*>(&Ks[idx]) = pk;
            }
            // V packed write: [d=lo][tok], tok = sub*16 + hi*4 + j
            {
                int tokv = sub * 16 + hi * 4;
                uint2 pv;
                pv.x = cvtpk(av[0] + bv_, av[1] + bv_);
                pv.y = cvtpk(av[2] + bv_, av[3] + bv_);
                *reinterpret_cast<uint2*>(&Vs[h * 2176 + lo * 136 + tokv]) = pv;
            }
        }
    }
    __syncthreads();

    // ---- Phase 3: attention; Wo conversion folded into its head ----
    {
        int lo2 = lane & 31, hi2 = lane >> 5;
        int swz = (lo2 & 4) << 1;            // tok&4 == lo2&4 for tok = t*32+lo2
        const f32x16 zero = {};

        bf16x8 kf[4];
#pragma unroll
        for (int t = 0; t < 4; ++t)
            kf[t] = *reinterpret_cast<const bf16x8*>(
                &Ks[(h << 11) + (((t * 32 + lo2) * 16 + hi2 * 8) ^ swz)]);
        __syncthreads();   // all waves' Ks reads done -> Ks region dead

        // Wo regs -> bf16 into dead Ks region; stores drain under the
        // qt-loop's compute (region disjoint from Qs/Vs/ctxs).
#pragma unroll
        for (int i = 0; i < 8; ++i) {
            int idx = i * 512 + tid;
            int n = idx & 127;
            int k0 = (idx >> 7) * 4;
            uint2 pw;
            pw.x = cvtpk(wpre[i][0], wpre[i][1]);
            pw.y = cvtpk(wpre[i][2], wpre[i][3]);
            *reinterpret_cast<uint2*>(wob + ((u32)(n * 256 + k0 * 2) ^ ((n & 7) << 4))) = pw;
        }

        for (int qt = 0; qt < 4; ++qt) {
            bf16x8 qf = *reinterpret_cast<const bf16x8*>(
                &Qs[(h << 11) + (((qt * 32 + lo2) * 16 + hi2 * 8) ^ swz)]);
            f32x16 s[4];
#pragma unroll
            for (int t = 0; t < 4; ++t)
                s[t] = __builtin_amdgcn_mfma_f32_32x32x16_bf16(kf[t], qf, zero, 0, 0, 0);

            // tree max (depth ~6)
            float mA[16];
#pragma unroll
            for (int i = 0; i < 16; ++i)
                mA[i] = fmaxf(fmaxf(s[0][i], s[1][i]), fmaxf(s[2][i], s[3][i]));
#pragma unroll
            for (int i = 0; i < 8; ++i) mA[i] = fmaxf(mA[i], mA[i + 8]);
#pragma unroll
            for (int i = 0; i < 4; ++i) mA[i] = fmaxf(mA[i], mA[i + 4]);
            float m = fmaxf(fmaxf(mA[0], mA[1]), fmaxf(mA[2], mA[3]));
            m = fmaxf(m, __shfl_xor(m, 32));
            float m2 = m * LOG2E;

            float sm0 = 0.f, sm1 = 0.f, sm2 = 0.f, sm3 = 0.f;
#pragma unroll
            for (int t = 0; t < 4; ++t)
#pragma unroll
                for (int r = 0; r < 16; ++r) {
                    float p = vexp2(__builtin_fmaf(s[t][r], LOG2E, -m2));
                    s[t][r] = p;
                    if (t == 0) sm0 += p; else if (t == 1) sm1 += p;
                    else if (t == 2) sm2 += p; else sm3 += p;
                }
            float sum = (sm0 + sm1) + (sm2 + sm3);
            sum += __shfl_xor(sum, 32);
            float inv = 1.f / sum;

            f32x16 o0 = {}, o1 = {};
#pragma unroll
            for (int c = 0; c < 8; ++c) {
                int t = c >> 1, hf = (c & 1) * 8;
                u32 x0 = cvtpk(s[t][hf + 0], s[t][hf + 1]);
                u32 x1 = cvtpk(s[t][hf + 2], s[t][hf + 3]);
                u32 y0 = cvtpk(s[t][hf + 4], s[t][hf + 5]);
                u32 y1 = cvtpk(s[t][hf + 6], s[t][hf + 7]);
                plswap(x0, y0);
                plswap(x1, y1);
                union { u32 wd[4]; bf16x8 v; } pb;
                pb.wd[0] = x0; pb.wd[1] = x1; pb.wd[2] = y0; pb.wd[3] = y1;
                bf16x8 va = *reinterpret_cast<const bf16x8*>(
                    &Vs[h * 2176 + (lo2 & 15) * 136 + c * 16 + hi2 * 8]);
                if (c & 1)
                    o1 = __builtin_amdgcn_mfma_f32_32x32x16_bf16(va, pb.v, o1, 0, 0, 0);
                else
                    o0 = __builtin_amdgcn_mfma_f32_32x32x16_bf16(va, pb.v, o0, 0, 0, 0);
            }

            int tok = qt * 32 + lo2;
            u32 off0 = (u32)(tok * 256 + h * 32 + 8 * hi2) ^ ((tok & 7) << 4);
            u32 off1 = (u32)(tok * 256 + h * 32 + 16 + 8 * hi2) ^ ((tok & 7) << 4);
            uint2 p0, p1;
            p0.x = cvtpk((o0[0] + o1[0]) * inv, (o0[1] + o1[1]) * inv);
            p0.y = cvtpk((o0[2] + o1[2]) * inv, (o0[3] + o1[3]) * inv);
            p1.x = cvtpk((o0[4] + o1[4]) * inv, (o0[5] + o1[5]) * inv);
            p1.y = cvtpk((o0[6] + o1[6]) * inv, (o0[7] + o1[7]) * inv);
            *reinterpret_cast<uint2*>(ctxs + off0) = p0;
            *reinterpret_cast<uint2*>(ctxs + off1) = p1;
        }
    }
    __syncthreads();   // ctx + wob both ready for all waves

    // ---- Phase 4: out-proj (r19 verbatim). Wave h does tokens
    // [h*16, h*16+16); col-contiguous scalar stores (coalesced). ----
    {
        f32x4 acc[8];
#pragma unroll
        for (int c = 0; c < 8; ++c) acc[c] = f32x4{0.f, 0.f, 0.f, 0.f};
#pragma unroll
        for (int kk = 0; kk < 4; ++kk) {
            int tokrow = h * 16 + lo;
            u32 aoff = (u32)(tokrow * 256 + kk * 64 + hi * 16) ^ ((tokrow & 7) << 4);
            bf16x8 a = *reinterpret_cast<const bf16x8*>(ctxs + aoff);
#pragma unroll
            for (int c = 0; c < 8; ++c) {
                u32 boff = (u32)((c * 16 + lo) * 256 + kk * 64 + hi * 16) ^ ((lo & 7) << 4);
                bf16x8 b = *reinterpret_cast<const bf16x8*>(wob + boff);
                acc[c] = __builtin_amdgcn_mfma_f32_16x16x32_bf16(a, b, acc[c], 0, 0, 0);
            }
        }
        // mask CSE: this thread's 4 token rows are t0+0..3
        int t0 = seq * 128 + h * 16 + hi * 4;
        float4 mk4 = *reinterpret_cast<const float4*>(mask + t0);
        float mk[4] = {mk4.x, mk4.y, mk4.z, mk4.w};
#pragma unroll
        for (int c = 0; c < 8; ++c) {
            int col = c * 16 + lo;
            float bval = bo[col];
#pragma unroll
            for (int j = 0; j < 4; ++j) {
                int t = t0 + j;
                out[(size_t)t * EMB + col] = (acc[c][j] + bval) * mk[j];
            }
        }
    }
}

// ---------------------------------------------------------------------------
extern "C" void kernel_launch(void* const* d_in, const int* in_sizes, int n_in,
                              void* d_out, int out_size, void* d_ws, size_t ws_size,
                              hipStream_t stream) {
    const float* pe   = (const float*)d_in[0];
    const float* mask = (const float*)d_in[1];
    const float* ln_g = (const float*)d_in[2];
    const float* ln_b = (const float*)d_in[3];
    const float* wq   = (const float*)d_in[4];
    const float* bq   = (const float*)d_in[5];
    const float* wk   = (const float*)d_in[6];
    const float* bk   = (const float*)d_in[7];
    const float* wv   = (const float*)d_in[8];
    const float* bv   = (const float*)d_in[9];
    const float* wo   = (const float*)d_in[10];
    const float* bo   = (const float*)d_in[11];
    float* out = (float*)d_out;

    hipLaunchKernelGGL(k_fused, dim3(256), dim3(512), 0, stream, pe, ln_g, ln_b,
                       wq, wk, wv, wo, bq, bk, bv, bo, mask, out);
}

// Round 21
// 24.271 us; speedup vs baseline: 1.0942x; 1.0002x over previous
//
#include <hip/hip_runtime.h>
#include <hip/hip_bf16.h>

typedef __attribute__((ext_vector_type(8))) short bf16x8;
typedef __attribute__((ext_vector_type(4))) float f32x4;
typedef __attribute__((ext_vector_type(16))) float f32x16;
typedef __attribute__((ext_vector_type(2))) unsigned int u32x2;
typedef unsigned short u16;
typedef unsigned int u32;

#define EMB 128
#define LOG2E 1.44269504088896f

static __device__ __forceinline__ u32 cvtpk(float a, float b) {
    u32 r;
    asm("v_cvt_pk_bf16_f32 %0, %1, %2" : "=v"(r) : "v"(a), "v"(b));
    return r;
}

static __device__ __forceinline__ float vexp2(float x) {
    float r;
    asm("v_exp_f32 %0, %1" : "=v"(r) : "v"(x));
    return r;
}

// exchange: a' = [a.lo32 | b.lo32(partner)], b' = [a.hi32(partner) | b.hi32]
static __device__ __forceinline__ void plswap(u32& a, u32& b) {
#if __has_builtin(__builtin_amdgcn_permlane32_swap)
    u32x2 r = __builtin_amdgcn_permlane32_swap(a, b, false, false);
    a = r[0]; b = r[1];
#else
    u32 sa = __shfl_xor(a, 32), sb = __shfl_xor(b, 32);
    bool hi = (threadIdx.x & 32) != 0;
    u32 na = hi ? sb : a;
    u32 nb = hi ? b : sa;
    a = na; b = nb;
#endif
}

// ---------------------------------------------------------------------------
// Single fully fused kernel (r20-green base). Sole delta this round: the
// phase-2 -> phase-3 __syncthreads() is removed. Rationale: phase 3's
// Qs/Ks/Vs reads are wave-private (wave h wrote head h's regions itself in
// phase 2); the only cross-wave hazard (wob overwriting all heads' Ks) is
// guarded by the RETAINED barrier after the kf loads. A wave-local fence
// (lgkmcnt(0) + "memory" + sched_barrier) orders this wave's own LDS
// writes before its reads (TBAA: u32 stores vs short-vector loads).
// LDS map (132 KB):
//   [0,      34816)  Xs   : LN'd X, [128 tok][136 u16]  (reused as ctxs)
//   [34816,  67584)  Qs   : [8 h][128 tok][16 d] u16, XOR-swz idx^((tok&4)<<1)
//   [67584, 100352)  Ks   : same as Qs (reused as swizzled Wo in phase 3)
//   [100352,135168)  Vs   : [8 h][16 d][136 tok-pitch] u16
__global__ void __launch_bounds__(512) k_fused(const float* __restrict__ pe,
        const float* __restrict__ g, const float* __restrict__ bia,
        const float* __restrict__ wq_f, const float* __restrict__ wk_f,
        const float* __restrict__ wv_f, const float* __restrict__ wo_f,
        const float* __restrict__ bq, const float* __restrict__ bk,
        const float* __restrict__ bv, const float* __restrict__ bo,
        const float* __restrict__ mask, float* __restrict__ out) {
    __shared__ __align__(16) char smem[135168];
    u16* Xs = reinterpret_cast<u16*>(smem);            // pitch 136
    u16* Qs = reinterpret_cast<u16*>(smem + 34816);
    u16* Ks = reinterpret_cast<u16*>(smem + 67584);
    u16* Vs = reinterpret_cast<u16*>(smem + 100352);
    char* ctxs = smem;                                  // 256B-pitch, swizzled
    char* wob = smem + 67584;                           // Wo bf16, 256B-pitch, swizzled

    int tid = threadIdx.x;
    int seq = blockIdx.x;
    int lane = tid & 63, h = tid >> 6;
    int lo = lane & 15, hi = lane >> 4;

    // ---- QKV W fragments: gather fp32 directly, pack with cvtpk (r16) ----
    bf16x8 bf[3][4];
    {
        const float* wsrc0 = wq_f + h * 16 + lo;
        const float* wsrc1 = wk_f + h * 16 + lo;
        const float* wsrc2 = wv_f + h * 16 + lo;
#pragma unroll
        for (int mat = 0; mat < 3; ++mat) {
            const float* ws = mat == 0 ? wsrc0 : mat == 1 ? wsrc1 : wsrc2;
#pragma unroll
            for (int kk = 0; kk < 4; ++kk) {
                const float* base = ws + (kk * 32 + hi * 8) * 128;
                union { u32 w[4]; bf16x8 v; } u;
                u.w[0] = cvtpk(base[0],   base[128]);
                u.w[1] = cvtpk(base[256], base[384]);
                u.w[2] = cvtpk(base[512], base[640]);
                u.w[3] = cvtpk(base[768], base[896]);
                bf[mat][kk] = u.v;
            }
        }
    }
    float4 bq4 = *reinterpret_cast<const float4*>(bq + h * 16 + hi * 4);
    float4 bk4 = *reinterpret_cast<const float4*>(bk + h * 16 + hi * 4);
    float bv_ = bv[h * 16 + lo];

    // ---- Wo prefetch (transposed ownership, r17): thread i owns (n, k0..k0+3).
    float wpre[8][4];
#pragma unroll
    for (int i = 0; i < 8; ++i) {
        int idx = i * 512 + tid;        // 0..4095
        int n = idx & 127;
        int k0 = (idx >> 7) * 4;
#pragma unroll
        for (int j = 0; j < 4; ++j)
            wpre[i][j] = wo_f[(k0 + j) * 128 + n];
    }

    // ---- Phase 1: LayerNorm, 4 threads/token, 128 tokens ----
    {
        int tl = tid >> 2;
        int q = tid & 3;
        const float4* src = reinterpret_cast<const float4*>(pe + (size_t)(seq * 128 + tl) * EMB);
        float4 v[8];
        float s = 0.f, ss = 0.f;
#pragma unroll
        for (int i = 0; i < 8; ++i) {
            v[i] = src[i * 4 + q];
            s += v[i].x + v[i].y + v[i].z + v[i].w;
            ss += v[i].x * v[i].x + v[i].y * v[i].y + v[i].z * v[i].z + v[i].w * v[i].w;
        }
        s += __shfl_xor(s, 1); ss += __shfl_xor(ss, 1);
        s += __shfl_xor(s, 2); ss += __shfl_xor(ss, 2);
        float mean = s * (1.f / EMB);
        float var = ss * (1.f / EMB) - mean * mean;
        float rstd = rsqrtf(var + 1e-5f);
#pragma unroll
        for (int i = 0; i < 8; ++i) {
            int c = i * 16 + q * 4;
            float4 gg = *reinterpret_cast<const float4*>(g + c);
            float4 bb = *reinterpret_cast<const float4*>(bia + c);
            uint2 packed;
            packed.x = cvtpk((v[i].x - mean) * rstd * gg.x + bb.x,
                             (v[i].y - mean) * rstd * gg.y + bb.y);
            packed.y = cvtpk((v[i].z - mean) * rstd * gg.z + bb.z,
                             (v[i].w - mean) * rstd * gg.w + bb.w);
            *reinterpret_cast<uint2*>(&Xs[tl * 136 + c]) = packed;
        }
    }
    __syncthreads();

    // ---- Phase 2: per-head QKV GEMM (W in regs) -> wave-private LDS ----
    {
#pragma unroll
        for (int sub = 0; sub < 8; ++sub) {
            bf16x8 a[4];
#pragma unroll
            for (int kk = 0; kk < 4; ++kk)
                a[kk] = *reinterpret_cast<const bf16x8*>(&Xs[(sub * 16 + lo) * 136 + kk * 32 + hi * 8]);
            f32x4 aq = {}, ak = {}, av = {};
#pragma unroll
            for (int kk = 0; kk < 4; ++kk) {
                // swapped: D col = token = lo, row = d = hi*4+j
                aq = __builtin_amdgcn_mfma_f32_16x16x32_bf16(bf[0][kk], a[kk], aq, 0, 0, 0);
                ak = __builtin_amdgcn_mfma_f32_16x16x32_bf16(bf[1][kk], a[kk], ak, 0, 0, 0);
                // normal: D col = d = lo, row = token = hi*4+j
                av = __builtin_amdgcn_mfma_f32_16x16x32_bf16(a[kk], bf[2][kk], av, 0, 0, 0);
            }
            // Q/K packed write: token = sub*16+lo, d = hi*4..hi*4+3
            {
                int tok = sub * 16 + lo;
                int idx = ((h << 11) + tok * 16 + hi * 4) ^ ((tok & 4) << 1);
                uint2 pq, pk;
                pq.x = cvtpk((aq[0] + bq4.x) * 0.25f, (aq[1] + bq4.y) * 0.25f);
                pq.y = cvtpk((aq[2] + bq4.z) * 0.25f, (aq[3] + bq4.w) * 0.25f);
                pk.x = cvtpk(ak[0] + bk4.x, ak[1] + bk4.y);
                pk.y = cvtpk(ak[2] + bk4.z, ak[3] + bk4.w);
                *reinterpret_cast<uint2*>(&Qs[idx]) = pq;
                *reinterpret_cast<uint2*>(&Ks[idx]) = pk;
            }
            // V packed write: [d=lo][tok], tok = sub*16 + hi*4 + j
            {
                int tokv = sub * 16 + hi * 4;
                uint2 pv;
                pv.x = cvtpk(av[0] + bv_, av[1] + bv_);
                pv.y = cvtpk(av[2] + bv_, av[3] + bv_);
                *reinterpret_cast<uint2*>(&Vs[h * 2176 + lo * 136 + tokv]) = pv;
            }
        }
    }
    // Wave-local fence (NOT a barrier): phase-3 reads head h's Qs/Ks/Vs,
    // all written by this wave above. Drain this wave's LDS queue and pin
    // program order across the TBAA boundary (u32 stores vs bf16x8 loads).
    asm volatile("s_waitcnt lgkmcnt(0)" ::: "memory");
    __builtin_amdgcn_sched_barrier(0);

    // ---- Phase 3: attention; Wo conversion folded into its head ----
    {
        int lo2 = lane & 31, hi2 = lane >> 5;
        int swz = (lo2 & 4) << 1;            // tok&4 == lo2&4 for tok = t*32+lo2
        const f32x16 zero = {};

        bf16x8 kf[4];
#pragma unroll
        for (int t = 0; t < 4; ++t)
            kf[t] = *reinterpret_cast<const bf16x8*>(
                &Ks[(h << 11) + (((t * 32 + lo2) * 16 + hi2 * 8) ^ swz)]);
        __syncthreads();   // ALL waves: phase-2 writes + own kf reads done
                           // -> Ks region globally dead, safe to overwrite

        // Wo regs -> bf16 into dead Ks region; stores drain under the
        // qt-loop's compute (region disjoint from Qs/Vs/ctxs).
#pragma unroll
        for (int i = 0; i < 8; ++i) {
            int idx = i * 512 + tid;
            int n = idx & 127;
            int k0 = (idx >> 7) * 4;
            uint2 pw;
            pw.x = cvtpk(wpre[i][0], wpre[i][1]);
            pw.y = cvtpk(wpre[i][2], wpre[i][3]);
            *reinterpret_cast<uint2*>(wob + ((u32)(n * 256 + k0 * 2) ^ ((n & 7) << 4))) = pw;
        }

        for (int qt = 0; qt < 4; ++qt) {
            bf16x8 qf = *reinterpret_cast<const bf16x8*>(
                &Qs[(h << 11) + (((qt * 32 + lo2) * 16 + hi2 * 8) ^ swz)]);
            f32x16 s[4];
#pragma unroll
            for (int t = 0; t < 4; ++t)
                s[t] = __builtin_amdgcn_mfma_f32_32x32x16_bf16(kf[t], qf, zero, 0, 0, 0);

            // tree max (depth ~6)
            float mA[16];
#pragma unroll
            for (int i = 0; i < 16; ++i)
                mA[i] = fmaxf(fmaxf(s[0][i], s[1][i]), fmaxf(s[2][i], s[3][i]));
#pragma unroll
            for (int i = 0; i < 8; ++i) mA[i] = fmaxf(mA[i], mA[i + 8]);
#pragma unroll
            for (int i = 0; i < 4; ++i) mA[i] = fmaxf(mA[i], mA[i + 4]);
            float m = fmaxf(fmaxf(mA[0], mA[1]), fmaxf(mA[2], mA[3]));
            m = fmaxf(m, __shfl_xor(m, 32));
            float m2 = m * LOG2E;

            float sm0 = 0.f, sm1 = 0.f, sm2 = 0.f, sm3 = 0.f;
#pragma unroll
            for (int t = 0; t < 4; ++t)
#pragma unroll
                for (int r = 0; r < 16; ++r) {
                    float p = vexp2(__builtin_fmaf(s[t][r], LOG2E, -m2));
                    s[t][r] = p;
                    if (t == 0) sm0 += p; else if (t == 1) sm1 += p;
                    else if (t == 2) sm2 += p; else sm3 += p;
                }
            float sum = (sm0 + sm1) + (sm2 + sm3);
            sum += __shfl_xor(sum, 32);
            float inv = 1.f / sum;

            f32x16 o0 = {}, o1 = {};
#pragma unroll
            for (int c = 0; c < 8; ++c) {
                int t = c >> 1, hf = (c & 1) * 8;
                u32 x0 = cvtpk(s[t][hf + 0], s[t][hf + 1]);
                u32 x1 = cvtpk(s[t][hf + 2], s[t][hf + 3]);
                u32 y0 = cvtpk(s[t][hf + 4], s[t][hf + 5]);
                u32 y1 = cvtpk(s[t][hf + 6], s[t][hf + 7]);
                plswap(x0, y0);
                plswap(x1, y1);
                union { u32 wd[4]; bf16x8 v; } pb;
                pb.wd[0] = x0; pb.wd[1] = x1; pb.wd[2] = y0; pb.wd[3] = y1;
                bf16x8 va = *reinterpret_cast<const bf16x8*>(
                    &Vs[h * 2176 + (lo2 & 15) * 136 + c * 16 + hi2 * 8]);
                if (c & 1)
                    o1 = __builtin_amdgcn_mfma_f32_32x32x16_bf16(va, pb.v, o1, 0, 0, 0);
                else
                    o0 = __builtin_amdgcn_mfma_f32_32x32x16_bf16(va, pb.v, o0, 0, 0, 0);
            }

            int tok = qt * 32 + lo2;
            u32 off0 = (u32)(tok * 256 + h * 32 + 8 * hi2) ^ ((tok & 7) << 4);
            u32 off1 = (u32)(tok * 256 + h * 32 + 16 + 8 * hi2) ^ ((tok & 7) << 4);
            uint2 p0, p1;
            p0.x = cvtpk((o0[0] + o1[0]) * inv, (o0[1] + o1[1]) * inv);
            p0.y = cvtpk((o0[2] + o1[2]) * inv, (o0[3] + o1[3]) * inv);
            p1.x = cvtpk((o0[4] + o1[4]) * inv, (o0[5] + o1[5]) * inv);
            p1.y = cvtpk((o0[6] + o1[6]) * inv, (o0[7] + o1[7]) * inv);
            *reinterpret_cast<uint2*>(ctxs + off0) = p0;
            *reinterpret_cast<uint2*>(ctxs + off1) = p1;
        }
    }
    __syncthreads();   // ctx + wob both ready for all waves

    // ---- Phase 4: out-proj (r19 verbatim). Wave h does tokens
    // [h*16, h*16+16); col-contiguous scalar stores (coalesced). ----
    {
        f32x4 acc[8];
#pragma unroll
        for (int c = 0; c < 8; ++c) acc[c] = f32x4{0.f, 0.f, 0.f, 0.f};
#pragma unroll
        for (int kk = 0; kk < 4; ++kk) {
            int tokrow = h * 16 + lo;
            u32 aoff = (u32)(tokrow * 256 + kk * 64 + hi * 16) ^ ((tokrow & 7) << 4);
            bf16x8 a = *reinterpret_cast<const bf16x8*>(ctxs + aoff);
#pragma unroll
            for (int c = 0; c < 8; ++c) {
                u32 boff = (u32)((c * 16 + lo) * 256 + kk * 64 + hi * 16) ^ ((lo & 7) << 4);
                bf16x8 b = *reinterpret_cast<const bf16x8*>(wob + boff);
                acc[c] = __builtin_amdgcn_mfma_f32_16x16x32_bf16(a, b, acc[c], 0, 0, 0);
            }
        }
        // mask CSE: this thread's 4 token rows are t0+0..3
        int t0 = seq * 128 + h * 16 + hi * 4;
        float4 mk4 = *reinterpret_cast<const float4*>(mask + t0);
        float mk[4] = {mk4.x, mk4.y, mk4.z, mk4.w};
#pragma unroll
        for (int c = 0; c < 8; ++c) {
            int col = c * 16 + lo;
            float bval = bo[col];
#pragma unroll
            for (int j = 0; j < 4; ++j) {
                int t = t0 + j;
                out[(size_t)t * EMB + col] = (acc[c][j] + bval) * mk[j];
            }
        }
    }
}

// ---------------------------------------------------------------------------
extern "C" void kernel_launch(void* const* d_in, const int* in_sizes, int n_in,
                              void* d_out, int out_size, void* d_ws, size_t ws_size,
                              hipStream_t stream) {
    const float* pe   = (const float*)d_in[0];
    const float* mask = (const float*)d_in[1];
    const float* ln_g = (const float*)d_in[2];
    const float* ln_b = (const float*)d_in[3];
    const float* wq   = (const float*)d_in[4];
    const float* bq   = (const float*)d_in[5];
    const float* wk   = (const float*)d_in[6];
    const float* bk   = (const float*)d_in[7];
    const float* wv   = (const float*)d_in[8];
    const float* bv   = (const float*)d_in[9];
    const float* wo   = (const float*)d_in[10];
    const float* bo   = (const float*)d_in[11];
    float* out = (float*)d_out;

    hipLaunchKernelGGL(k_fused, dim3(256), dim3(512), 0, stream, pe, ln_g, ln_b,
                       wq, wk, wv, wo, bq, bk, bv, bo, mask, out);
}